// Round 15
// baseline (47.867 us; speedup 1.0000x reference)
//
#include <hip/hip_runtime.h>

// Policy MLP via split-precision bf16 MFMA (round 15: C=64 cols/wave).
// B=131072, D=32, L=40 hidden + final 32->1.
//
// r10-r14 establish: wall == SUM of pipe demands (MFMA 931 + VALU 512 +
// LDS 1152 cyc/CU-layer = 2595 vs 2560 measured); overlap engineering is
// futile (MFMA shares the SIMD MACs with VALU; LDS drains while MACs idle).
// The only wave-count-scaled term is weight/bias LDS traffic (6 reads per
// wave-layer regardless of C). Round-15: C=64 per wave -> waves halve ->
// LDS term halves (1152->576). MFMA/VALU totals unchanged. Predicted sum
// 2019 cyc/CU-layer ~= 34us.
//
// Config: 4x 16-col tiles per wave, 24 MFMAs/wave-layer, 2048 waves,
// 512-thr blocks, 1 block/CU (157KB LDS: bias-all + layers 0-37; 38-40 via
// L1/global). __launch_bounds__(512,2) -> 256-VGPR budget, 2 waves/SIMD.
//
// Math per layer (unchanged): acc = Whi*xhi (C=bias); += Wlo*xhi; += Whi*xlo
// pi(g,j) = 4g+j (j<4) | 16+4g+(j-4) on both A and B => D feeds next B
// in-lane; truncation split via v_perm_b32 (hi's error carried by lo).

#define NB 131072
#define DD 32
#define NL 40
#define BIAS_BYTES ((NL + 1) * 32 * 4)       // 5248, compact fp32 bias
#define WTAB_OFF   BIAS_BYTES
#define WTAB_BYTES ((NL + 1) * 4 * 64 * 16)  // 167936
#define LDS_LAYERS 38
#define LDS_BYTES  (BIAS_BYTES + LDS_LAYERS * 4096)  // 160896 <= 163840

typedef short bf16x8 __attribute__((ext_vector_type(8)));
typedef float f32x4 __attribute__((ext_vector_type(4)));

union Frag { int4 q; int i[4]; bf16x8 v; };
union BFrag { float4 q; f32x4 v; };

__device__ inline unsigned f2bf(float f) {  // fp32 -> bf16 bits, RNE
  unsigned u = __float_as_uint(f);
  return (u + 0x7fffu + ((u >> 16) & 1u)) >> 16;
}
__device__ inline float bf2f(unsigned s) { return __int_as_float((int)(s << 16)); }

// ---- table build ----------------------------------------------------------
// d_ws layout: [bias compact 5248 B][wtab 41 layers x 4096 B].
// wtab[l][p][lane]: p=0: W[m][pi] hi, p=1: W[16+m][pi] hi, p=2/3: lo parts.
__global__ __launch_bounds__(64) void build_tables(
    const float* __restrict__ Wh, const float* __restrict__ bh,
    const float* __restrict__ Wout, const float* __restrict__ bout,
    char* __restrict__ ws) {
  const int l = blockIdx.x;      // 0..40 (40 == output layer)
  const int lane = threadIdx.x;  // 0..63
  const int m = lane & 15, g = lane >> 4;
  int4* wtab = (int4*)(ws + WTAB_OFF);
  float* bc = (float*)ws;
  for (int p = 0; p < 4; ++p) {
    const int row = (p & 1) ? (16 + m) : m;
    const bool lopart = (p >= 2);
    int wds[4];
    for (int w = 0; w < 4; ++w) {
      unsigned wd = 0;
      for (int e = 0; e < 2; ++e) {
        const int j = 2 * w + e;
        const int k = (j < 4) ? (4 * g + j) : (16 + 4 * g + (j - 4));  // pi
        float v;
        if (l < NL) v = Wh[(l * 32 + row) * 32 + k];
        else        v = (row == 0) ? Wout[k] : 0.f;  // final: row0 = W_out
        unsigned hi = f2bf(v);
        unsigned val = lopart ? f2bf(v - bf2f(hi)) : hi;
        wd |= val << (16 * e);
      }
      wds[w] = (int)wd;
    }
    wtab[(l * 4 + p) * 64 + lane] = make_int4(wds[0], wds[1], wds[2], wds[3]);
  }
  if (lane < 32) {  // compact bias, one float per output row
    float bv = (l < NL) ? bh[l * 32 + lane] : ((lane == 0) ? bout[0] : 0.f);
    bc[l * 32 + lane] = bv;
  }
}

// ---- main kernel ----------------------------------------------------------
// Truncation split: hi = packed high-halves of (a,b) via one v_perm_b32;
// lo = packed high-halves of the exact residuals.
__device__ inline void split2(float a, float b, int& hi, int& lo) {
  const unsigned ia = __float_as_uint(a), ib = __float_as_uint(b);
  hi = (int)__builtin_amdgcn_perm(ia, ib, 0x03020706u);
  const float ha = __int_as_float((int)(ia & 0xffff0000u));
  const float hb = __int_as_float((int)(ib & 0xffff0000u));
  const float la = a - ha, lb = b - hb;  // exact
  lo = (int)__builtin_amdgcn_perm(__float_as_uint(la), __float_as_uint(lb),
                                  0x03020706u);
}

#define MFMA16(A, B, C) __builtin_amdgcn_mfma_f32_16x16x32_bf16((A), (B), (C), 0, 0, 0)

__global__ __launch_bounds__(512, 2) void policy_mfma(
    const float* __restrict__ state, const char* __restrict__ tab,
    float* __restrict__ out) {
  extern __shared__ char smem[];
  const int tid = threadIdx.x;
  const int lane = tid & 63;
  const int n = lane & 15, g = lane >> 4;
  const int wid = blockIdx.x * 8 + (tid >> 6);
  const int bbase = wid * 64;  // 64 batch cols per wave (4 x 16-col tiles)

  // ---- stage bias + 38 layers of weights into LDS (~157 KB, one-time) ----
  {
    const int4* src = (const int4*)tab;
    int4* dst = (int4*)smem;
    for (int i = tid; i < LDS_BYTES / 16; i += 512) dst[i] = src[i];
  }

  // Layer-0 B frags from state (no LDS dependency; overlaps staging)
  Frag bhi[4], blo[4];
#pragma unroll
  for (int t = 0; t < 4; ++t) {
    const float* xr = state + (size_t)(bbase + 16 * t + n) * DD;
    float4 xa = *(const float4*)(xr + 4 * g);
    float4 xc = *(const float4*)(xr + 16 + 4 * g);
    split2(xa.x, xa.y, bhi[t].i[0], blo[t].i[0]);
    split2(xa.z, xa.w, bhi[t].i[1], blo[t].i[1]);
    split2(xc.x, xc.y, bhi[t].i[2], blo[t].i[2]);
    split2(xc.z, xc.w, bhi[t].i[3], blo[t].i[3]);
  }

  __syncthreads();  // LDS tables ready

  const int4* lw = (const int4*)(smem + WTAB_OFF) + lane;  // LDS weights l<38
  const float* bc = (const float*)smem;                     // LDS bias, all l
  const int4* gw = (const int4*)(tab + WTAB_OFF) + lane;    // global l>=38

#pragma unroll
  for (int l = 0; l < NL; ++l) {
    Frag w0h, w1h, w0l, w1l;
    const int4* WP = (l < LDS_LAYERS) ? lw : gw;  // compile-time per iter
    w0h.q = WP[l * 256 + 0];
    w1h.q = WP[l * 256 + 64];
    w0l.q = WP[l * 256 + 128];
    w1l.q = WP[l * 256 + 192];
    BFrag c0, c1;
    c0.q = *(const float4*)(bc + l * 32 + 4 * g);       // rows 4g..4g+3
    c1.q = *(const float4*)(bc + l * 32 + 16 + 4 * g);  // rows 16+4g..

    // 8 independent 3-deep chains (4 col-tiles x 2 row-halves), interleaved
    f32x4 a0[4], a1[4];
#pragma unroll
    for (int t = 0; t < 4; ++t) a0[t] = MFMA16(w0h.v, bhi[t].v, c0.v);
#pragma unroll
    for (int t = 0; t < 4; ++t) a1[t] = MFMA16(w1h.v, bhi[t].v, c1.v);
#pragma unroll
    for (int t = 0; t < 4; ++t) a0[t] = MFMA16(w0l.v, bhi[t].v, a0[t]);
#pragma unroll
    for (int t = 0; t < 4; ++t) a1[t] = MFMA16(w1l.v, bhi[t].v, a1[t]);
#pragma unroll
    for (int t = 0; t < 4; ++t) a0[t] = MFMA16(w0h.v, blo[t].v, a0[t]);
#pragma unroll
    for (int t = 0; t < 4; ++t) a1[t] = MFMA16(w1h.v, blo[t].v, a1[t]);

    // relu + trunc-split; a0[t] reg r -> slot r, a1[t] reg r -> slot 4+r
#pragma unroll
    for (int t = 0; t < 4; ++t) {
      split2(fmaxf(a0[t][0], 0.f), fmaxf(a0[t][1], 0.f), bhi[t].i[0], blo[t].i[0]);
      split2(fmaxf(a0[t][2], 0.f), fmaxf(a0[t][3], 0.f), bhi[t].i[1], blo[t].i[1]);
      split2(fmaxf(a1[t][0], 0.f), fmaxf(a1[t][1], 0.f), bhi[t].i[2], blo[t].i[2]);
      split2(fmaxf(a1[t][2], 0.f), fmaxf(a1[t][3], 0.f), bhi[t].i[3], blo[t].i[3]);
    }
  }

  // ---- final layer l=40 (W rows 16-31 zero: only w0h/w0l + c0; row0=W_out)
  float res[4];
  {
    Frag w0h, w0l;
    w0h.q = gw[NL * 256 + 0];
    w0l.q = gw[NL * 256 + 128];
    BFrag c0;
    c0.q = *(const float4*)(bc + NL * 32 + 4 * g);
    f32x4 a0[4];
#pragma unroll
    for (int t = 0; t < 4; ++t) a0[t] = MFMA16(w0h.v, bhi[t].v, c0.v);
#pragma unroll
    for (int t = 0; t < 4; ++t) a0[t] = MFMA16(w0l.v, bhi[t].v, a0[t]);
#pragma unroll
    for (int t = 0; t < 4; ++t) a0[t] = MFMA16(w0h.v, blo[t].v, a0[t]);
#pragma unroll
    for (int t = 0; t < 4; ++t) res[t] = a0[t][0];  // row 0, reg 0, lanes g==0
  }

  if (lane < 16) {
#pragma unroll
    for (int t = 0; t < 4; ++t) out[bbase + 16 * t + n] = res[t];
  }
}

extern "C" void kernel_launch(void* const* d_in, const int* in_sizes, int n_in,
                              void* d_out, int out_size, void* d_ws, size_t ws_size,
                              hipStream_t stream) {
  const float* state = (const float*)d_in[0];
  const float* Wh    = (const float*)d_in[1];
  const float* bh    = (const float*)d_in[2];
  const float* Wout  = (const float*)d_in[3];
  const float* bout  = (const float*)d_in[4];
  float* out = (float*)d_out;

  build_tables<<<NL + 1, 64, 0, stream>>>(Wh, bh, Wout, bout, (char*)d_ws);

  // 131072/64 = 2048 waves; 512-thr blocks (8 waves) -> 256 blocks = 1/CU.
  policy_mfma<<<256, 512, LDS_BYTES, stream>>>(state, (const char*)d_ws, out);
}

// Round 17
// 45.241 us; speedup vs baseline: 1.0580x; 1.0580x over previous
//
#include <hip/hip_runtime.h>

// Policy MLP via split-precision bf16 MFMA (round 17 = round 16 with the
// s_sleep constant-arg fix).
// B=131072, D=32, L=40 hidden + final 32->1.
//
// Change vs round 13 (single variable): per-wave phase stagger after the
// staging barrier -- wave w sleeps ~64*w cycles via a wave-uniform switch
// with CONSTANT s_sleep arguments (the builtin requires a literal).
// Rationale: r5-r15 plateau at 42-47us with ~45% idle. All waves run
// byte-identical unrolled code from a common barrier -> phase-locked: LDS
// bursts, MFMA chains, split chains collide; every latency is exposed to
// every wave simultaneously. Waves are independent after staging, so an
// initial stagger persists for all 41 layers.
//
// Base (r13): C=32 cols/wave, 16 waves/CU (1024-thr block, 1 block/CU via
// 157KB LDS), layers 0-37 + all bias in LDS, 38-40 via L1; register
// double-buffer prefetch of next layer's fragments.
//
// Math per layer: acc = Whi*xhi (C=bias); += Wlo*xhi; += Whi*xlo
// pi(g,j) = 4g+j (j<4) | 16+4g+(j-4) on both A and B => D feeds next B
// in-lane; truncation split via v_perm_b32 (hi's error carried by lo).

#define NB 131072
#define DD 32
#define NL 40
#define BIAS_BYTES ((NL + 1) * 32 * 4)       // 5248, compact fp32 bias
#define WTAB_OFF   BIAS_BYTES
#define WTAB_BYTES ((NL + 1) * 4 * 64 * 16)  // 167936
#define LDS_LAYERS 38
#define LDS_BYTES  (BIAS_BYTES + LDS_LAYERS * 4096)  // 160896 <= 163840

typedef short bf16x8 __attribute__((ext_vector_type(8)));
typedef float f32x4 __attribute__((ext_vector_type(4)));

union Frag { int4 q; int i[4]; bf16x8 v; };
union BFrag { float4 q; f32x4 v; };

__device__ inline unsigned f2bf(float f) {  // fp32 -> bf16 bits, RNE
  unsigned u = __float_as_uint(f);
  return (u + 0x7fffu + ((u >> 16) & 1u)) >> 16;
}
__device__ inline float bf2f(unsigned s) { return __int_as_float((int)(s << 16)); }

// ---- table build ----------------------------------------------------------
// d_ws layout: [bias compact 5248 B][wtab 41 layers x 4096 B].
// wtab[l][p][lane]: p=0: W[m][pi] hi, p=1: W[16+m][pi] hi, p=2/3: lo parts.
__global__ __launch_bounds__(64) void build_tables(
    const float* __restrict__ Wh, const float* __restrict__ bh,
    const float* __restrict__ Wout, const float* __restrict__ bout,
    char* __restrict__ ws) {
  const int l = blockIdx.x;      // 0..40 (40 == output layer)
  const int lane = threadIdx.x;  // 0..63
  const int m = lane & 15, g = lane >> 4;
  int4* wtab = (int4*)(ws + WTAB_OFF);
  float* bc = (float*)ws;
  for (int p = 0; p < 4; ++p) {
    const int row = (p & 1) ? (16 + m) : m;
    const bool lopart = (p >= 2);
    int wds[4];
    for (int w = 0; w < 4; ++w) {
      unsigned wd = 0;
      for (int e = 0; e < 2; ++e) {
        const int j = 2 * w + e;
        const int k = (j < 4) ? (4 * g + j) : (16 + 4 * g + (j - 4));  // pi
        float v;
        if (l < NL) v = Wh[(l * 32 + row) * 32 + k];
        else        v = (row == 0) ? Wout[k] : 0.f;  // final: row0 = W_out
        unsigned hi = f2bf(v);
        unsigned val = lopart ? f2bf(v - bf2f(hi)) : hi;
        wd |= val << (16 * e);
      }
      wds[w] = (int)wd;
    }
    wtab[(l * 4 + p) * 64 + lane] = make_int4(wds[0], wds[1], wds[2], wds[3]);
  }
  if (lane < 32) {  // compact bias, one float per output row
    float bv = (l < NL) ? bh[l * 32 + lane] : ((lane == 0) ? bout[0] : 0.f);
    bc[l * 32 + lane] = bv;
  }
}

// ---- main kernel ----------------------------------------------------------
// Truncation split: hi = packed high-halves of (a,b) via one v_perm_b32;
// lo = packed high-halves of the exact residuals.
__device__ inline void split2(float a, float b, int& hi, int& lo) {
  const unsigned ia = __float_as_uint(a), ib = __float_as_uint(b);
  hi = (int)__builtin_amdgcn_perm(ia, ib, 0x03020706u);
  const float ha = __int_as_float((int)(ia & 0xffff0000u));
  const float hb = __int_as_float((int)(ib & 0xffff0000u));
  const float la = a - ha, lb = b - hb;  // exact
  lo = (int)__builtin_amdgcn_perm(__float_as_uint(la), __float_as_uint(lb),
                                  0x03020706u);
}

// Wave-uniform stagger: s_sleep needs a literal arg -> constant-case switch.
__device__ inline void wave_stagger(int w) {
  switch (w) {
    case 0: break;
    case 1: __builtin_amdgcn_s_sleep(1); break;
    case 2: __builtin_amdgcn_s_sleep(2); break;
    case 3: __builtin_amdgcn_s_sleep(3); break;
    case 4: __builtin_amdgcn_s_sleep(4); break;
    case 5: __builtin_amdgcn_s_sleep(5); break;
    case 6: __builtin_amdgcn_s_sleep(6); break;
    case 7: __builtin_amdgcn_s_sleep(7); break;
    case 8: __builtin_amdgcn_s_sleep(8); break;
    case 9: __builtin_amdgcn_s_sleep(9); break;
    case 10: __builtin_amdgcn_s_sleep(10); break;
    case 11: __builtin_amdgcn_s_sleep(11); break;
    case 12: __builtin_amdgcn_s_sleep(12); break;
    case 13: __builtin_amdgcn_s_sleep(13); break;
    case 14: __builtin_amdgcn_s_sleep(14); break;
    default: __builtin_amdgcn_s_sleep(15); break;
  }
}

#define MFMA16(A, B, C) __builtin_amdgcn_mfma_f32_16x16x32_bf16((A), (B), (C), 0, 0, 0)

__global__ __launch_bounds__(1024, 4) void policy_mfma(
    const float* __restrict__ state, const char* __restrict__ tab,
    float* __restrict__ out) {
  extern __shared__ char smem[];
  const int tid = threadIdx.x;
  const int lane = tid & 63;
  const int n = lane & 15, g = lane >> 4;
  const int wInB = tid >> 6;  // 0..15
  const int wid = blockIdx.x * 16 + wInB;
  const int bbase = wid * 32;  // 32 batch cols per wave (2 x 16-col tiles)

  // ---- stage bias + 38 layers of weights into LDS (~157 KB, one-time) ----
  {
    const int4* src = (const int4*)tab;
    int4* dst = (int4*)smem;
    for (int i = tid; i < LDS_BYTES / 16; i += 1024) dst[i] = src[i];
  }

  // Layer-0 B frags from state (no LDS dependency; overlaps staging)
  Frag bhi[2], blo[2];
#pragma unroll
  for (int t = 0; t < 2; ++t) {
    const float* xr = state + (size_t)(bbase + 16 * t + n) * DD;
    float4 xa = *(const float4*)(xr + 4 * g);
    float4 xc = *(const float4*)(xr + 16 + 4 * g);
    split2(xa.x, xa.y, bhi[t].i[0], blo[t].i[0]);
    split2(xa.z, xa.w, bhi[t].i[1], blo[t].i[1]);
    split2(xc.x, xc.y, bhi[t].i[2], blo[t].i[2]);
    split2(xc.z, xc.w, bhi[t].i[3], blo[t].i[3]);
  }

  __syncthreads();  // LDS tables ready

  // ---- PHASE STAGGER: wave w starts ~64*w cycles late; waves are fully
  // independent from here on so the offset persists through all 41 layers.
  wave_stagger(wInB);

  const int4* lw = (const int4*)(smem + WTAB_OFF) + lane;  // LDS weights l<38
  const float* bc = (const float*)smem;                     // LDS bias, all l
  const int4* gw = (const int4*)(tab + WTAB_OFF) + lane;    // global l>=38

  // Double-buffered register prefetch (parity index; full unroll => static).
  Frag Wf[2][4];
  BFrag Cf[2][2];
  Wf[0][0].q = lw[0];
  Wf[0][1].q = lw[64];
  Wf[0][2].q = lw[128];
  Wf[0][3].q = lw[192];
  Cf[0][0].q = *(const float4*)(bc + 4 * g);
  Cf[0][1].q = *(const float4*)(bc + 16 + 4 * g);

#pragma unroll
  for (int l = 0; l < NL; ++l) {
    const int cur = l & 1, nxt = cur ^ 1;

    // ---- prefetch layer l+1 fragments into the other buffer ----
    {
      const int lp = l + 1;
      const int4* src = (lp < LDS_LAYERS) ? lw : gw;  // compile-time per iter
      Wf[nxt][0].q = src[lp * 256 + 0];
      Wf[nxt][1].q = src[lp * 256 + 64];
      Wf[nxt][2].q = src[lp * 256 + 128];
      Wf[nxt][3].q = src[lp * 256 + 192];
      Cf[nxt][0].q = *(const float4*)(bc + lp * 32 + 4 * g);
      Cf[nxt][1].q = *(const float4*)(bc + lp * 32 + 16 + 4 * g);
    }

    // ---- compute layer l: 4 independent 3-deep chains ----
    f32x4 a00 = MFMA16(Wf[cur][0].v, bhi[0].v, Cf[cur][0].v);
    f32x4 a01 = MFMA16(Wf[cur][1].v, bhi[0].v, Cf[cur][1].v);
    f32x4 a10 = MFMA16(Wf[cur][0].v, bhi[1].v, Cf[cur][0].v);
    f32x4 a11 = MFMA16(Wf[cur][1].v, bhi[1].v, Cf[cur][1].v);
    a00 = MFMA16(Wf[cur][2].v, bhi[0].v, a00);
    a01 = MFMA16(Wf[cur][3].v, bhi[0].v, a01);
    a10 = MFMA16(Wf[cur][2].v, bhi[1].v, a10);
    a11 = MFMA16(Wf[cur][3].v, bhi[1].v, a11);
    a00 = MFMA16(Wf[cur][0].v, blo[0].v, a00);
    a01 = MFMA16(Wf[cur][1].v, blo[0].v, a01);
    a10 = MFMA16(Wf[cur][0].v, blo[1].v, a10);
    a11 = MFMA16(Wf[cur][1].v, blo[1].v, a11);

    // relu + trunc-split; D reg r of accX0 -> slot j=r, accX1 -> slot 4+r
    split2(fmaxf(a00[0], 0.f), fmaxf(a00[1], 0.f), bhi[0].i[0], blo[0].i[0]);
    split2(fmaxf(a00[2], 0.f), fmaxf(a00[3], 0.f), bhi[0].i[1], blo[0].i[1]);
    split2(fmaxf(a01[0], 0.f), fmaxf(a01[1], 0.f), bhi[0].i[2], blo[0].i[2]);
    split2(fmaxf(a01[2], 0.f), fmaxf(a01[3], 0.f), bhi[0].i[3], blo[0].i[3]);
    split2(fmaxf(a10[0], 0.f), fmaxf(a10[1], 0.f), bhi[1].i[0], blo[1].i[0]);
    split2(fmaxf(a10[2], 0.f), fmaxf(a10[3], 0.f), bhi[1].i[1], blo[1].i[1]);
    split2(fmaxf(a11[0], 0.f), fmaxf(a11[1], 0.f), bhi[1].i[2], blo[1].i[2]);
    split2(fmaxf(a11[2], 0.f), fmaxf(a11[3], 0.f), bhi[1].i[3], blo[1].i[3]);
  }

  // ---- final layer l=40 (parity 0 buffer). W rows 16-31 zero: only frags
  // 0 (hi, rows 0-15) and 2 (lo) + bias c0 needed; row0 = W_out.
  float res0, res1;
  {
    f32x4 a00 = MFMA16(Wf[0][0].v, bhi[0].v, Cf[0][0].v);
    f32x4 a10 = MFMA16(Wf[0][0].v, bhi[1].v, Cf[0][0].v);
    a00 = MFMA16(Wf[0][2].v, bhi[0].v, a00);
    a10 = MFMA16(Wf[0][2].v, bhi[1].v, a10);
    a00 = MFMA16(Wf[0][0].v, blo[0].v, a00);
    a10 = MFMA16(Wf[0][0].v, blo[1].v, a10);
    res0 = a00[0];  // row 0 lives in reg 0 of lanes g==0 (lane<16)
    res1 = a10[0];
  }

  if (lane < 16) {
    out[bbase + n] = res0;
    out[bbase + 16 + n] = res1;
  }
}

extern "C" void kernel_launch(void* const* d_in, const int* in_sizes, int n_in,
                              void* d_out, int out_size, void* d_ws, size_t ws_size,
                              hipStream_t stream) {
  const float* state = (const float*)d_in[0];
  const float* Wh    = (const float*)d_in[1];
  const float* bh    = (const float*)d_in[2];
  const float* Wout  = (const float*)d_in[3];
  const float* bout  = (const float*)d_in[4];
  float* out = (float*)d_out;

  build_tables<<<NL + 1, 64, 0, stream>>>(Wh, bh, Wout, bout, (char*)d_ws);

  // 4096 waves; 16 waves (1024 thr) per block; 256 blocks = 1/CU (LDS-pinned).
  policy_mfma<<<256, 1024, LDS_BYTES, stream>>>(state, (const char*)d_ws, out);
}